// Round 1
// baseline (112.961 us; speedup 1.0000x reference)
//
#include <hip/hip_runtime.h>
#include <hip/hip_bf16.h>

// Problem: T=4096 targets x E=65536 edges. For each target t:
//   mask[e]  = (src[e]==t_src) | (dst[e]==t_dst)
//   is_tgt[e]= (src[e]==t_src) & (dst[e]==t_dst)
//   K = sum(mask); lse = log(sum_{mask} exp(score[e])); idx = first is_tgt
//   loss_t = exists ? (lse - score[idx]) / K : 0
// out = sum_t loss_t / T
//
// No max-subtraction needed: scores are N(0,1), exp(score) in [~0.01,~100],
// K ~ 13 terms -> fp32 sum is safe and matches the reference's logsumexp.

#define NT   8     // targets per block
#define BLK  256   // threads per block

__global__ __launch_bounds__(BLK) void la_loss_main(
    const int* __restrict__ src, const int* __restrict__ dst,
    const float* __restrict__ score,
    const int* __restrict__ tsrc, const int* __restrict__ tdst,
    float* __restrict__ partial, int E, int T)
{
    const int tid   = threadIdx.x;
    const int tbase = blockIdx.x * NT;
    if (tbase >= T) return;

    // Wave-uniform target loads (clamped so partial last block is safe).
    int ts[NT], td[NT];
#pragma unroll
    for (int j = 0; j < NT; ++j) {
        int tj = tbase + j; if (tj > T - 1) tj = T - 1;
        ts[j] = tsrc[tj];
        td[j] = tdst[tj];
    }

    float S[NT];   // sum of exp(score) over mask
    float Kc[NT];  // count of mask
    int   idx[NT]; // min index with is_tgt
#pragma unroll
    for (int j = 0; j < NT; ++j) { S[j] = 0.0f; Kc[j] = 0.0f; idx[j] = 0x7fffffff; }

    // Strided, vectorized edge sweep: each thread owns 4 consecutive edges
    // per iteration; 256 threads cover 1024 consecutive edges (coalesced 16B).
    for (int it = tid * 4; it < E; it += BLK * 4) {
        const int4   vs = *reinterpret_cast<const int4*>(src + it);
        const int4   vd = *reinterpret_cast<const int4*>(dst + it);
        const float4 sc = *reinterpret_cast<const float4*>(score + it);
        const int   es[4] = { vs.x, vs.y, vs.z, vs.w };
        const int   ed[4] = { vd.x, vd.y, vd.z, vd.w };
        const float ev[4] = { __expf(sc.x), __expf(sc.y), __expf(sc.z), __expf(sc.w) };
#pragma unroll
        for (int j = 0; j < NT; ++j) {
#pragma unroll
            for (int k = 0; k < 4; ++k) {
                const bool ms = (es[k] == ts[j]);
                const bool md = (ed[k] == td[j]);
                const bool m  = ms | md;
                S[j]  += m ? ev[k] : 0.0f;
                Kc[j] += m ? 1.0f  : 0.0f;
                idx[j] = (ms & md) ? min(idx[j], it + k) : idx[j];
            }
        }
    }

    // Wave-level butterfly reduce (wave = 64 lanes on gfx950).
#pragma unroll
    for (int j = 0; j < NT; ++j) {
        for (int off = 32; off > 0; off >>= 1) {
            S[j]  += __shfl_down(S[j],  off);
            Kc[j] += __shfl_down(Kc[j], off);
            idx[j] = min(idx[j], __shfl_down(idx[j], off));
        }
    }

    // Cross-wave reduce through LDS (4 waves per block).
    __shared__ float sS[4][NT];
    __shared__ float sK[4][NT];
    __shared__ int   sI[4][NT];
    const int wave = tid >> 6;
    const int lane = tid & 63;
    if (lane == 0) {
#pragma unroll
        for (int j = 0; j < NT; ++j) { sS[wave][j] = S[j]; sK[wave][j] = Kc[j]; sI[wave][j] = idx[j]; }
    }
    __syncthreads();

    if (tid < NT && (tbase + tid) < T) {
        float Ssum = 0.0f, Ksum = 0.0f;
        int im = 0x7fffffff;
#pragma unroll
        for (int w = 0; w < 4; ++w) {
            Ssum += sS[w][tid];
            Ksum += sK[w][tid];
            im    = min(im, sI[w][tid]);
        }
        const bool exists = (im != 0x7fffffff);
        float loss = 0.0f;
        if (exists) {
            const float tgt_logit = score[im];
            loss = (logf(Ssum) - tgt_logit) / Ksum;
        }
        partial[tbase + tid] = loss;
    }
}

// Deterministic final reduction: fixed-order strided sum + tree reduce.
__global__ __launch_bounds__(256) void la_loss_reduce(
    const float* __restrict__ partial, float* __restrict__ out, int T)
{
    float s = 0.0f;
    for (int i = threadIdx.x; i < T; i += 256) s += partial[i];
    for (int off = 32; off > 0; off >>= 1) s += __shfl_down(s, off);
    __shared__ float acc[4];
    if ((threadIdx.x & 63) == 0) acc[threadIdx.x >> 6] = s;
    __syncthreads();
    if (threadIdx.x == 0) out[0] = (acc[0] + acc[1] + acc[2] + acc[3]) / (float)T;
}

extern "C" void kernel_launch(void* const* d_in, const int* in_sizes, int n_in,
                              void* d_out, int out_size, void* d_ws, size_t ws_size,
                              hipStream_t stream) {
    const int*   edge_index = (const int*)d_in[0];   // (2, E) int32
    const float* score      = (const float*)d_in[1]; // (E,)   f32
    const int*   target     = (const int*)d_in[2];   // (2, T) int32
    // d_in[3] = num_nodes (unused)

    const int E = in_sizes[0] / 2;
    const int T = in_sizes[2] / 2;

    const int* src  = edge_index;
    const int* dst  = edge_index + E;
    const int* tsrc = target;
    const int* tdst = target + T;

    float* partial = (float*)d_ws;  // T floats of scratch

    const int nblocks = (T + NT - 1) / NT;
    la_loss_main<<<nblocks, BLK, 0, stream>>>(src, dst, score, tsrc, tdst, partial, E, T);
    la_loss_reduce<<<1, 256, 0, stream>>>(partial, (float*)d_out, T);
}

// Round 2
// 88.549 us; speedup vs baseline: 1.2757x; 1.2757x over previous
//
#include <hip/hip_runtime.h>
#include <hip/hip_bf16.h>
#include <stdint.h>

// LinearAssignmentLossCE via inclusion-exclusion + hash join: O(E + T)
// instead of O(T*E).
//
// For target t=(a,b):
//   mask = (src==a) | (dst==b)
//   K    = cntS[a] + cntD[b] - cntBoth(a,b)          (|A|+|B|-|A∩B|)
//   lse  = log( sumS[a] + sumD[b] - sumBoth(a,b) )   (sums of exp(score))
//   idx  = min{ e : src[e]==a && dst[e]==b }          (== argmax(is_tgt))
//   loss = exists ? (lse - score[idx]) / K : 0
// out = sum_t loss / T
//
// exp(score) is safe unscaled: scores ~ N(0,1), so exp in [~0.01,~100] and
// ~13-term sums stay well inside fp32 range (round-1 absmax was 0.0).
//
// "Both" aggregates live in an open-addressing hash on key = src*N + dst
// (N=10000 -> key < 1e8 < 2^32). Float atomic order varies only inside
// ~6-element bucket sums -> ~1e-7 output jitter vs 4.5e-3 threshold.

#define HLOG 17
#define HSZ  (1u << HLOG)   // 131072 hash slots (load factor ~0.5)
#define NCAP 16384          // max num_nodes supported by fast path (N=10000)

// ws layout, 32-bit words:
//   [0,H)         keys  (u32, 0xFFFFFFFF = empty)
//   [H,2H)        hsum  (f32)  sum exp over exact-key edges
//   [2H,3H)       hcnt  (u32)
//   [3H,4H)       hmin  (i32)  min edge index with exact key
//   [4H,4H+NCAP)  sumS  (f32)  per-node sum exp over src matches
//   [+NCAP)       sumD  (f32)
//   [+NCAP)       cntS  (u32)
//   [+NCAP)       cntD  (u32)
#define WORDS_TOTAL (4 * HSZ + 4 * NCAP)

__device__ __forceinline__ uint32_t hmix(uint32_t k) {
    k *= 2654435761u;
    k ^= k >> 15;
    return k;
}

__global__ __launch_bounds__(256) void la_init(uint32_t* __restrict__ ws) {
    int i = blockIdx.x * 256 + threadIdx.x;
    const int stride = gridDim.x * 256;
    for (; i < (int)WORDS_TOTAL; i += stride) {
        uint32_t v;
        if (i < (int)HSZ)            v = 0xFFFFFFFFu;  // keys: empty
        else if (i < (int)(3 * HSZ)) v = 0u;           // hsum, hcnt
        else if (i < (int)(4 * HSZ)) v = 0x7FFFFFFFu;  // hmin: INT_MAX
        else                         v = 0u;           // node aggregates
        ws[i] = v;
    }
}

__global__ __launch_bounds__(256) void la_edges(
    const int* __restrict__ src, const int* __restrict__ dst,
    const float* __restrict__ score, const int* __restrict__ pN,
    uint32_t* __restrict__ ws, int E)
{
    const int N = *pN;  // wave-uniform scalar load
    uint32_t* keys = ws;
    float*    hsum = (float*)(ws + HSZ);
    uint32_t* hcnt = ws + 2 * HSZ;
    int*      hmin = (int*)(ws + 3 * HSZ);
    float*    sumS = (float*)(ws + 4 * HSZ);
    float*    sumD = sumS + NCAP;
    uint32_t* cntS = (uint32_t*)(sumD + NCAP);
    uint32_t* cntD = cntS + NCAP;

    const int e = blockIdx.x * 256 + threadIdx.x;
    if (e >= E) return;

    const int s = src[e], d = dst[e];
    const float ev = __expf(score[e]);

    atomicAdd(&sumS[s], ev);
    atomicAdd(&sumD[d], ev);
    atomicAdd(&cntS[s], 1u);
    atomicAdd(&cntD[d], 1u);

    const uint32_t key = (uint32_t)s * (uint32_t)N + (uint32_t)d;
    uint32_t h = hmix(key) & (HSZ - 1);
    while (true) {
        const uint32_t prev = atomicCAS(&keys[h], 0xFFFFFFFFu, key);
        if (prev == 0xFFFFFFFFu || prev == key) break;
        h = (h + 1) & (HSZ - 1);
    }
    atomicAdd(&hsum[h], ev);
    atomicAdd(&hcnt[h], 1u);
    atomicMin(&hmin[h], e);
}

// Single block, 1024 threads (16 waves on one CU hide L2 lookup latency),
// fixed-order tree reduce -> deterministic final sum structure.
__global__ __launch_bounds__(1024) void la_targets(
    const int* __restrict__ tsrc, const int* __restrict__ tdst,
    const float* __restrict__ score, const int* __restrict__ pN,
    const uint32_t* __restrict__ ws, float* __restrict__ out, int T)
{
    const int N = *pN;
    const uint32_t* keys = ws;
    const float*    hsum = (const float*)(ws + HSZ);
    const uint32_t* hcnt = ws + 2 * HSZ;
    const int*      hmin = (const int*)(ws + 3 * HSZ);
    const float*    sumS = (const float*)(ws + 4 * HSZ);
    const float*    sumD = sumS + NCAP;
    const uint32_t* cntS = (const uint32_t*)(sumD + NCAP);
    const uint32_t* cntD = cntS + NCAP;

    float local = 0.0f;
    for (int t = threadIdx.x; t < T; t += 1024) {
        const int a = tsrc[t], b = tdst[t];
        const uint32_t key = (uint32_t)a * (uint32_t)N + (uint32_t)b;
        uint32_t h = hmix(key) & (HSZ - 1);
        int slot = -1;
        while (true) {
            const uint32_t k2 = keys[h];
            if (k2 == key) { slot = (int)h; break; }
            if (k2 == 0xFFFFFFFFu) break;  // not present -> exists=false
            h = (h + 1) & (HSZ - 1);
        }
        if (slot >= 0) {
            const float S = sumS[a] + sumD[b] - hsum[slot];
            const float K = (float)(int)(cntS[a] + cntD[b] - hcnt[slot]);
            const int   idx = hmin[slot];
            local += (logf(S) - score[idx]) / K;
        }
    }

    for (int off = 32; off > 0; off >>= 1) local += __shfl_down(local, off);
    __shared__ float acc[16];
    if ((threadIdx.x & 63) == 0) acc[threadIdx.x >> 6] = local;
    __syncthreads();
    if (threadIdx.x == 0) {
        float s = 0.0f;
#pragma unroll
        for (int w = 0; w < 16; ++w) s += acc[w];
        out[0] = s / (float)T;
    }
}

// ---------------------------------------------------------------------------
// Fallback: round-1 brute force (used only if ws_size is too small for the
// hash tables; needs just T*4 bytes of ws).
// ---------------------------------------------------------------------------
#define NT   8
#define BLK  256

__global__ __launch_bounds__(BLK) void la_loss_main(
    const int* __restrict__ src, const int* __restrict__ dst,
    const float* __restrict__ score,
    const int* __restrict__ tsrc, const int* __restrict__ tdst,
    float* __restrict__ partial, int E, int T)
{
    const int tid   = threadIdx.x;
    const int tbase = blockIdx.x * NT;
    if (tbase >= T) return;

    int ts[NT], td[NT];
#pragma unroll
    for (int j = 0; j < NT; ++j) {
        int tj = tbase + j; if (tj > T - 1) tj = T - 1;
        ts[j] = tsrc[tj];
        td[j] = tdst[tj];
    }

    float S[NT]; float Kc[NT]; int idx[NT];
#pragma unroll
    for (int j = 0; j < NT; ++j) { S[j] = 0.0f; Kc[j] = 0.0f; idx[j] = 0x7fffffff; }

    for (int it = tid * 4; it < E; it += BLK * 4) {
        const int4   vs = *reinterpret_cast<const int4*>(src + it);
        const int4   vd = *reinterpret_cast<const int4*>(dst + it);
        const float4 sc = *reinterpret_cast<const float4*>(score + it);
        const int   es[4] = { vs.x, vs.y, vs.z, vs.w };
        const int   ed[4] = { vd.x, vd.y, vd.z, vd.w };
        const float ev[4] = { __expf(sc.x), __expf(sc.y), __expf(sc.z), __expf(sc.w) };
#pragma unroll
        for (int j = 0; j < NT; ++j) {
#pragma unroll
            for (int k = 0; k < 4; ++k) {
                const bool ms = (es[k] == ts[j]);
                const bool md = (ed[k] == td[j]);
                const bool m  = ms | md;
                S[j]  += m ? ev[k] : 0.0f;
                Kc[j] += m ? 1.0f  : 0.0f;
                idx[j] = (ms & md) ? min(idx[j], it + k) : idx[j];
            }
        }
    }

#pragma unroll
    for (int j = 0; j < NT; ++j) {
        for (int off = 32; off > 0; off >>= 1) {
            S[j]  += __shfl_down(S[j],  off);
            Kc[j] += __shfl_down(Kc[j], off);
            idx[j] = min(idx[j], __shfl_down(idx[j], off));
        }
    }

    __shared__ float sS[4][NT];
    __shared__ float sK[4][NT];
    __shared__ int   sI[4][NT];
    const int wave = tid >> 6;
    const int lane = tid & 63;
    if (lane == 0) {
#pragma unroll
        for (int j = 0; j < NT; ++j) { sS[wave][j] = S[j]; sK[wave][j] = Kc[j]; sI[wave][j] = idx[j]; }
    }
    __syncthreads();

    if (tid < NT && (tbase + tid) < T) {
        float Ssum = 0.0f, Ksum = 0.0f;
        int im = 0x7fffffff;
#pragma unroll
        for (int w = 0; w < 4; ++w) {
            Ssum += sS[w][tid]; Ksum += sK[w][tid]; im = min(im, sI[w][tid]);
        }
        float loss = 0.0f;
        if (im != 0x7fffffff) loss = (logf(Ssum) - score[im]) / Ksum;
        partial[tbase + tid] = loss;
    }
}

__global__ __launch_bounds__(256) void la_loss_reduce(
    const float* __restrict__ partial, float* __restrict__ out, int T)
{
    float s = 0.0f;
    for (int i = threadIdx.x; i < T; i += 256) s += partial[i];
    for (int off = 32; off > 0; off >>= 1) s += __shfl_down(s, off);
    __shared__ float acc[4];
    if ((threadIdx.x & 63) == 0) acc[threadIdx.x >> 6] = s;
    __syncthreads();
    if (threadIdx.x == 0) out[0] = (acc[0] + acc[1] + acc[2] + acc[3]) / (float)T;
}

// ---------------------------------------------------------------------------

extern "C" void kernel_launch(void* const* d_in, const int* in_sizes, int n_in,
                              void* d_out, int out_size, void* d_ws, size_t ws_size,
                              hipStream_t stream) {
    const int*   edge_index = (const int*)d_in[0];   // (2, E) int32
    const float* score      = (const float*)d_in[1]; // (E,)   f32
    const int*   target     = (const int*)d_in[2];   // (2, T) int32
    const int*   pN         = (const int*)d_in[3];   // num_nodes (scalar, on device)

    const int E = in_sizes[0] / 2;
    const int T = in_sizes[2] / 2;

    const int* src  = edge_index;
    const int* dst  = edge_index + E;
    const int* tsrc = target;
    const int* tdst = target + T;

    const size_t need = (size_t)WORDS_TOTAL * 4;
    if (ws_size >= need) {
        uint32_t* ws = (uint32_t*)d_ws;
        la_init<<<256, 256, 0, stream>>>(ws);
        la_edges<<<(E + 255) / 256, 256, 0, stream>>>(src, dst, score, pN, ws, E);
        la_targets<<<1, 1024, 0, stream>>>(tsrc, tdst, score, pN, ws,
                                           (float*)d_out, T);
    } else {
        float* partial = (float*)d_ws;  // T floats
        la_loss_main<<<(T + NT - 1) / NT, BLK, 0, stream>>>(src, dst, score,
                                                            tsrc, tdst, partial, E, T);
        la_loss_reduce<<<1, 256, 0, stream>>>(partial, (float*)d_out, T);
    }
}